// Round 5
// baseline (283.885 us; speedup 1.0000x reference)
//
#include <hip/hip_runtime.h>
#include <hip/hip_bf16.h>

typedef _Float16 f16;
typedef _Float16 half8 __attribute__((ext_vector_type(8)));
typedef _Float16 half4 __attribute__((ext_vector_type(4)));
typedef float floatx4 __attribute__((ext_vector_type(4)));

#define BM 64

// ---- ws layout (f16 element offsets) ----
#define WA_OFF 0         // 65536 f16 : WaT frag order (NT=16,KT=8)
#define WB_OFF 65536     // 18432 f16 : WbT (NT=9, KT=4)  nt 0-7=W2, 8=W12
#define WC_OFF 83968     // 2048 f16  : WcT (NT=1, KT=4)  rows 0-3 = W22 cols
#define WF2_OFF 86016    // 4096 f16  : Wf2T [4][NT=2,KT=1]
#define WSF_BYTE_OFF 180224
// wsf (float offsets)
#define BA_OFF 0      // 256: b1 | bf1
#define BB_OFF 256    // 144: b2 | b12
#define BCC_OFF 400   // 4  : b22
#define BF2_OFF 404   // 128: bf2
#define WFIN_OFF 532  // 32
#define BFIN_OFF 564  // 1

__global__ __launch_bounds__(256) void prep_kernel(
    const float* __restrict__ ctx, const float* __restrict__ W1,
    const float* __restrict__ b1, const float* __restrict__ W2,
    const float* __restrict__ b2, const float* __restrict__ W12,
    const float* __restrict__ b12, const float* __restrict__ W22,
    const float* __restrict__ b22, const float* __restrict__ Wf1,
    const float* __restrict__ bf1, const float* __restrict__ Wf2,
    const float* __restrict__ bf2, const float* __restrict__ Wfin,
    const float* __restrict__ bfin, f16* __restrict__ wsh,
    float* __restrict__ wsf)
{
  int tid = blockIdx.x * 256 + threadIdx.x;
  if (tid < 65536) {
    int j = tid & 7, l = (tid >> 3) & 63, kt = (tid >> 9) & 7, nt = tid >> 12;
    int k = kt * 32 + ((l >> 4) << 3) + j, n = nt * 16 + (l & 15);
    float v;
    if (n < 128) v = ctx[k] * W1[k * 128 + n];
    else { int c = n - 128; v = Wf1[((c >> 5) * 256 + k) * 32 + (c & 31)]; }
    wsh[tid] = (f16)v;
  } else if (tid < WB_OFF + 18432) {
    int o = tid - WB_OFF;
    int j = o & 7, l = (o >> 3) & 63, kt = (o >> 9) & 3, nt = o >> 11;
    int k = kt * 32 + ((l >> 4) << 3) + j, n = nt * 16 + (l & 15);
    float v = (n < 128) ? W2[k * 128 + n] : W12[k * 16 + (n - 128)];
    wsh[tid] = (f16)v;
  } else if (tid < WC_OFF + 2048) {
    int o = tid - WC_OFF;
    int j = o & 7, l = (o >> 3) & 63, kt = (o >> 9) & 3;
    int k = kt * 32 + ((l >> 4) << 3) + j, n = l & 15;
    float v = (n < 4) ? W22[k * 4 + n] : 0.f;
    wsh[tid] = (f16)v;
  } else if (tid < WF2_OFF + 4096) {
    int o = tid - WF2_OFF;
    int j = o & 7, l = (o >> 3) & 63, ent = o >> 9;
    int e = ent >> 1, nt = ent & 1;
    int k = ((l >> 4) << 3) + j, n = nt * 16 + (l & 15);
    wsh[tid] = (f16)Wf2[(e * 32 + k) * 32 + n];
  } else if (tid < 90112 + 565) {
    int o = tid - 90112;
    float v;
    if (o < 128) v = b1[o];
    else if (o < 256) v = bf1[o - 128];
    else if (o < 384) v = b2[o - 256];
    else if (o < 400) v = b12[o - 384];
    else if (o < 404) v = b22[o - 400];
    else if (o < 532) v = bf2[o - 404];
    else if (o < 564) v = Wfin[o - 532];
    else v = bfin[0];
    wsf[o] = v;
  }
}

#define MFMA16(A, Bv, C) __builtin_amdgcn_mfma_f32_16x16x32_f16(A, Bv, C, 0, 0, 0)

// Wave-local design: each wave owns 16 rows end-to-end. ZERO __syncthreads.
// Per-wave LDS region (9216 B): G tile 16 rows x 512B (x -> h|o1 -> h2|in2,
// all overwrites same-wave, DS ops are in-order per wave) + 1 KB c1-transpose
// scratch. 4 waves x 9216 = 36864 B -> 4 blocks/CU. Cross-wave coupling: none.
#define WAVE_LDS 9216
#define SCR_OFF 8192

__global__ __launch_bounds__(256, 2) void fused_kernel(
    const float* __restrict__ x, const f16* __restrict__ wsh,
    const float* __restrict__ wsf, float* __restrict__ out)
{
  __shared__ __attribute__((aligned(16))) char lds[36864];
  const int t = threadIdx.x;
  const int lane = t & 63;
  const int w = t >> 6;
  const int l15 = lane & 15;
  const int l4 = lane >> 4;
  char* const wb = lds + w * WAVE_LDS;
  const size_t base = (size_t)blockIdx.x * BM + (size_t)w * 16;
  const int sw = (l15 & 7) << 4;

  // ---- stage this wave's 16 rows of x -> f16 swizzled ----
#pragma unroll
  for (int it = 0; it < 8; ++it) {
    int rl = it * 2 + (lane >> 5);
    int k0 = (lane & 31) << 3;
    const float4* xv = (const float4*)(x + (base + (size_t)rl) * 256 + k0);
    float4 a = xv[0], b = xv[1];
    half8 hv;
    hv[0] = (f16)a.x; hv[1] = (f16)a.y; hv[2] = (f16)a.z; hv[3] = (f16)a.w;
    hv[4] = (f16)b.x; hv[5] = (f16)b.y; hv[6] = (f16)b.z; hv[7] = (f16)b.w;
    *(half8*)(wb + ((rl * 512 + k0 * 2) ^ ((rl & 7) << 4))) = hv;
  }

  // ---- GEMM1: all 16 n-tiles for this wave's rows; h|o1 overlay x in-wave ----
  {
    floatx4 acc[16];
#pragma unroll
    for (int nt = 0; nt < 16; ++nt) acc[nt] = (floatx4){0.f, 0.f, 0.f, 0.f};
    for (int kt = 0; kt < 8; ++kt) {
      half8 Bx = *(const half8*)(wb + ((l15 * 512 + kt * 64 + (l4 << 4)) ^ sw));
#pragma unroll
      for (int nt = 0; nt < 16; ++nt) {
        half8 Wf = *(const half8*)(wsh + WA_OFF + (size_t)((nt * 8 + kt) * 64 + lane) * 8);
        acc[nt] = MFMA16(Wf, Bx, acc[nt]);
      }
    }
#pragma unroll
    for (int nt = 0; nt < 16; ++nt) {
      int c0 = nt * 16 + l4 * 4;
      float4 bias = *(const float4*)(wsf + BA_OFF + c0);
      half4 hv;
#pragma unroll
      for (int i = 0; i < 4; ++i) hv[i] = (f16)fmaxf(acc[nt][i] + ((const float*)&bias)[i], 0.f);
      *(half4*)(wb + ((l15 * 512 + c0 * 2) ^ sw)) = hv;
    }
  }

  // ---- GEMM2: h2 (overlay h in-wave) + L1 logits in registers ----
  float4 c1v;  // this lane (row l15, e=l4) -> c1[e][f=0..3]
  {
    floatx4 acc2[9];
#pragma unroll
    for (int nt = 0; nt < 9; ++nt) acc2[nt] = (floatx4){0.f, 0.f, 0.f, 0.f};
    for (int kt = 0; kt < 4; ++kt) {
      half8 Bh = *(const half8*)(wb + ((l15 * 512 + kt * 64 + (l4 << 4)) ^ sw));
#pragma unroll
      for (int nt = 0; nt < 9; ++nt) {
        half8 Wf = *(const half8*)(wsh + WB_OFF + (size_t)((nt * 4 + kt) * 64 + lane) * 8);
        acc2[nt] = MFMA16(Wf, Bh, acc2[nt]);
      }
    }
#pragma unroll
    for (int nt = 0; nt < 8; ++nt) {
      int c0 = nt * 16 + l4 * 4;
      float4 bias = *(const float4*)(wsf + BB_OFF + c0);
      half4 hv;
#pragma unroll
      for (int i = 0; i < 4; ++i) hv[i] = (f16)fmaxf(acc2[nt][i] + ((const float*)&bias)[i], 0.f);
      *(half4*)(wb + ((l15 * 512 + c0 * 2) ^ sw)) = hv;
    }
    // L1 logits: lane (row=l15, e=l4) holds cols 128 + l4*4 + i -> logit[e=l4][f=i]
    float4 biasL = *(const float4*)(wsf + BB_OFF + 128 + l4 * 4);
    float lg[4], mx[4];
#pragma unroll
    for (int i = 0; i < 4; ++i) lg[i] = acc2[8][i] + ((const float*)&biasL)[i];
    // softmax over e (across the 4 l4-groups), per f=i
#pragma unroll
    for (int i = 0; i < 4; ++i) {
      float m = lg[i];
      m = fmaxf(m, __shfl_xor(m, 16));
      m = fmaxf(m, __shfl_xor(m, 32));
      mx[i] = m;
    }
    float ex[4], sm[4];
#pragma unroll
    for (int i = 0; i < 4; ++i) {
      ex[i] = __expf(lg[i] - mx[i]);
      float s = ex[i];
      s += __shfl_xor(s, 16);
      s += __shfl_xor(s, 32);
      sm[i] = s;
    }
#pragma unroll
    for (int i = 0; i < 4; ++i) ((float*)&c1v)[i] = ex[i] / sm[i];
  }

  // ---- transpose c1 within wave via per-wave scratch (1 KB) ----
  f16 c1h[4];  // at lane (row l15, f=l4): c1[e=j][f] as f16
  {
    *(float4*)(wb + SCR_OFF + l15 * 64 + l4 * 16) = c1v;
#pragma unroll
    for (int j = 0; j < 4; ++j)
      c1h[j] = (f16)(*(const float*)(wb + SCR_OFF + l15 * 64 + j * 16 + l4 * 4));
  }

  // ---- GEMM3: L2 logits; c2 fully in-lane (l4==0 lanes hold all 4) ----
  float4 c2v;
  {
    floatx4 acc3 = (floatx4){0.f, 0.f, 0.f, 0.f};
#pragma unroll
    for (int kt = 0; kt < 4; ++kt) {
      half8 Bh2 = *(const half8*)(wb + ((l15 * 512 + kt * 64 + (l4 << 4)) ^ sw));
      half8 Wf = *(const half8*)(wsh + WC_OFF + (size_t)(kt * 64 + lane) * 8);
      acc3 = MFMA16(Wf, Bh2, acc3);
    }
    float4 bias = *(const float4*)(wsf + BCC_OFF);
    float q0 = acc3[0] + bias.x, q1 = acc3[1] + bias.y;
    float q2 = acc3[2] + bias.z, q3 = acc3[3] + bias.w;
    float m2 = fmaxf(fmaxf(q0, q1), fmaxf(q2, q3));
    float f0 = __expf(q0 - m2), f1 = __expf(q1 - m2);
    float f2 = __expf(q2 - m2), f3 = __expf(q3 - m2);
    float inv2 = 1.f / (f0 + f1 + f2 + f3);
    c2v.x = f0 * inv2; c2v.y = f1 * inv2; c2v.z = f2 * inv2; c2v.w = f3 * inv2;
    // meaningful only at l4==0 lanes (cols 0-3); others hold zero-padded cols
  }

  // ---- mix: in2[r][h][f] = sum_e o1[r][h][e]*c1[e][f], lane (r=l15, f=l4) ----
  {
    half8 res[4];
#pragma unroll
    for (int h8 = 0; h8 < 4; ++h8) {
      half8 o0 = *(const half8*)(wb + ((l15 * 512 + 256 + 0   + h8 * 16) ^ sw));
      half8 o1v = *(const half8*)(wb + ((l15 * 512 + 256 + 64  + h8 * 16) ^ sw));
      half8 o2v = *(const half8*)(wb + ((l15 * 512 + 256 + 128 + h8 * 16) ^ sw));
      half8 o3v = *(const half8*)(wb + ((l15 * 512 + 256 + 192 + h8 * 16) ^ sw));
      half8 r = o0 * c1h[0];
      r = r + o1v * c1h[1];
      r = r + o2v * c1h[2];
      r = r + o3v * c1h[3];
      res[h8] = r;
    }
    // all o1 reads above complete (in-order DS) before these same-region writes
#pragma unroll
    for (int h8 = 0; h8 < 4; ++h8)
      *(half8*)(wb + ((l15 * 512 + 256 + l4 * 64 + h8 * 16) ^ sw)) = res[h8];
  }

  // ---- GEMM4: per expert e, o2 = relu(in2_e @ Wf2_e); fused Wfin + c2 reduce ----
  {
    float4 wf0 = *(const float4*)(wsf + WFIN_OFF + l4 * 4);
    float4 wf1 = *(const float4*)(wsf + WFIN_OFF + 16 + l4 * 4);
    float total = 0.f;
#pragma unroll
    for (int e = 0; e < 4; ++e) {
      half8 Bi = *(const half8*)(wb + ((l15 * 512 + 256 + e * 64 + (l4 << 4)) ^ sw));
      floatx4 a0 = (floatx4){0.f, 0.f, 0.f, 0.f}, a1 = a0;
      half8 Wf0v = *(const half8*)(wsh + WF2_OFF + (size_t)((e * 2 + 0) * 64 + lane) * 8);
      half8 Wf1v = *(const half8*)(wsh + WF2_OFF + (size_t)((e * 2 + 1) * 64 + lane) * 8);
      a0 = MFMA16(Wf0v, Bi, a0);
      a1 = MFMA16(Wf1v, Bi, a1);
      float4 b0 = *(const float4*)(wsf + BF2_OFF + e * 32 + l4 * 4);
      float4 b1 = *(const float4*)(wsf + BF2_OFF + e * 32 + 16 + l4 * 4);
      float s = 0.f;
#pragma unroll
      for (int i = 0; i < 4; ++i) {
        s += fmaxf(a0[i] + ((const float*)&b0)[i], 0.f) * ((const float*)&wf0)[i];
        s += fmaxf(a1[i] + ((const float*)&b1)[i], 0.f) * ((const float*)&wf1)[i];
      }
      s += __shfl_xor(s, 16);
      s += __shfl_xor(s, 32);
      float c2e = __shfl(((const float*)&c2v)[e], l15);  // from lane (l15, l4=0)
      total += s * c2e;
    }
    if (l4 == 0) out[base + l15] = total + wsf[BFIN_OFF];
  }
}

extern "C" void kernel_launch(void* const* d_in, const int* in_sizes, int n_in,
                              void* d_out, int out_size, void* d_ws, size_t ws_size,
                              hipStream_t stream) {
  (void)in_sizes; (void)n_in; (void)ws_size;
  const float* x    = (const float*)d_in[0];
  const float* ctx  = (const float*)d_in[1];
  const float* W1   = (const float*)d_in[2];
  const float* b1   = (const float*)d_in[3];
  const float* W2   = (const float*)d_in[4];
  const float* b2   = (const float*)d_in[5];
  const float* W12  = (const float*)d_in[6];
  const float* b12  = (const float*)d_in[7];
  const float* W22  = (const float*)d_in[8];
  const float* b22  = (const float*)d_in[9];
  const float* Wf1  = (const float*)d_in[10];
  const float* bf1  = (const float*)d_in[11];
  const float* Wf2  = (const float*)d_in[12];
  const float* bf2  = (const float*)d_in[13];
  const float* Wfin = (const float*)d_in[14];
  const float* bfin = (const float*)d_in[15];

  f16* wsh = (f16*)d_ws;
  float* wsf = (float*)((char*)d_ws + WSF_BYTE_OFF);

  prep_kernel<<<355, 256, 0, stream>>>(ctx, W1, b1, W2, b2, W12, b12, W22, b22,
                                       Wf1, bf1, Wf2, bf2, Wfin, bfin, wsh, wsf);

  int nblocks = 262144 / BM;  // 4096
  fused_kernel<<<nblocks, 256, 0, stream>>>(x, wsh, wsf, (float*)d_out);
}

// Round 6
// 118.193 us; speedup vs baseline: 2.4019x; 2.4019x over previous
//
#include <hip/hip_runtime.h>
#include <hip/hip_bf16.h>

typedef _Float16 f16;
typedef _Float16 half8 __attribute__((ext_vector_type(8)));
typedef _Float16 half4 __attribute__((ext_vector_type(4)));
typedef float floatx4 __attribute__((ext_vector_type(4)));

#define BM 64

// ---- ws layout (f16 element offsets) ----
#define WA_OFF 0         // 65536 f16 : WaT frag order (NT=16,KT=8)
#define WB_OFF 65536     // 18432 f16 : WbT (NT=9, KT=4)  nt 0-7=W2, 8=W12
#define WC_OFF 83968     // 2048 f16  : WcT (NT=1, KT=4)  rows 0-3 = W22 cols
#define WF2_OFF 86016    // 4096 f16  : Wf2T [4][NT=2,KT=1]
#define WSF_BYTE_OFF 180224
// wsf (float offsets)
#define BA_OFF 0      // 256: b1 | bf1
#define BB_OFF 256    // 144: b2 | b12
#define BCC_OFF 400   // 4  : b22
#define BF2_OFF 404   // 128: bf2
#define WFIN_OFF 532  // 32
#define BFIN_OFF 564  // 1

__global__ __launch_bounds__(256) void prep_kernel(
    const float* __restrict__ ctx, const float* __restrict__ W1,
    const float* __restrict__ b1, const float* __restrict__ W2,
    const float* __restrict__ b2, const float* __restrict__ W12,
    const float* __restrict__ b12, const float* __restrict__ W22,
    const float* __restrict__ b22, const float* __restrict__ Wf1,
    const float* __restrict__ bf1, const float* __restrict__ Wf2,
    const float* __restrict__ bf2, const float* __restrict__ Wfin,
    const float* __restrict__ bfin, f16* __restrict__ wsh,
    float* __restrict__ wsf)
{
  int tid = blockIdx.x * 256 + threadIdx.x;
  if (tid < 65536) {
    int j = tid & 7, l = (tid >> 3) & 63, kt = (tid >> 9) & 7, nt = tid >> 12;
    int k = kt * 32 + ((l >> 4) << 3) + j, n = nt * 16 + (l & 15);
    float v;
    if (n < 128) v = ctx[k] * W1[k * 128 + n];
    else { int c = n - 128; v = Wf1[((c >> 5) * 256 + k) * 32 + (c & 31)]; }
    wsh[tid] = (f16)v;
  } else if (tid < WB_OFF + 18432) {
    int o = tid - WB_OFF;
    int j = o & 7, l = (o >> 3) & 63, kt = (o >> 9) & 3, nt = o >> 11;
    int k = kt * 32 + ((l >> 4) << 3) + j, n = nt * 16 + (l & 15);
    float v = (n < 128) ? W2[k * 128 + n] : W12[k * 16 + (n - 128)];
    wsh[tid] = (f16)v;
  } else if (tid < WC_OFF + 2048) {
    int o = tid - WC_OFF;
    int j = o & 7, l = (o >> 3) & 63, kt = (o >> 9) & 3;
    int k = kt * 32 + ((l >> 4) << 3) + j, n = l & 15;
    float v = (n < 4) ? W22[k * 4 + n] : 0.f;
    wsh[tid] = (f16)v;
  } else if (tid < WF2_OFF + 4096) {
    int o = tid - WF2_OFF;
    int j = o & 7, l = (o >> 3) & 63, ent = o >> 9;
    int e = ent >> 1, nt = ent & 1;
    int k = ((l >> 4) << 3) + j, n = nt * 16 + (l & 15);
    wsh[tid] = (f16)Wf2[(e * 32 + k) * 32 + n];
  } else if (tid < 90112 + 565) {
    int o = tid - 90112;
    float v;
    if (o < 128) v = b1[o];
    else if (o < 256) v = bf1[o - 128];
    else if (o < 384) v = b2[o - 256];
    else if (o < 400) v = b12[o - 384];
    else if (o < 404) v = b22[o - 400];
    else if (o < 532) v = bf2[o - 404];
    else if (o < 564) v = Wfin[o - 532];
    else v = bfin[0];
    wsf[o] = v;
  }
}

#define MFMA16(A, Bv, C) __builtin_amdgcn_mfma_f32_16x16x32_f16(A, Bv, C, 0, 0, 0)

// LDS map (bytes), 51 KB -> 3 blocks/CU of 512 threads = 24 waves/CU:
//  G   0..32767   [64][512B] f16 swz : x -> (h | o1) -> (in2 | o1)
//       (in2 overlays DEAD h region; mix is row-sliced per wave -> no convoy)
//  H2  32768..49151 [64][256B] f16 swz : h2
//  L1  49152..51199 [64][16] f16 logits ; part [64][8] f32 overlays after use
//  C2  51200..52223 [64][4] f32
#define H2_OFF 32768
#define L1_OFF 49152
#define PART_OFF 49152
#define C2_OFF 51200

__global__ __launch_bounds__(512, 6) void fused_kernel(
    const float* __restrict__ x, const f16* __restrict__ wsh,
    const float* __restrict__ wsf, float* __restrict__ out)
{
  __shared__ __attribute__((aligned(16))) char lds[52224];
  const int t = threadIdx.x;       // 0..511
  const int lane = t & 63;
  const int w = t >> 6;            // 0..7
  const int l15 = lane & 15;
  const int l4 = lane >> 4;
  const int sw = (l15 & 7) << 4;
  const size_t base = (size_t)blockIdx.x * BM;

  // ---- stage x tile -> G (f16, swizzled) ----
#pragma unroll
  for (int it = 0; it < 4; ++it) {
    int c = it * 512 + t;
    int r = c >> 5;
    int k0 = (c & 31) << 3;
    const float4* xv = (const float4*)(x + (base + (size_t)r) * 256 + k0);
    float4 a = xv[0], b = xv[1];
    half8 hv;
    hv[0] = (f16)a.x; hv[1] = (f16)a.y; hv[2] = (f16)a.z; hv[3] = (f16)a.w;
    hv[4] = (f16)b.x; hv[5] = (f16)b.y; hv[6] = (f16)b.z; hv[7] = (f16)b.w;
    *(half8*)(lds + ((r * 512 + k0 * 2) ^ ((r & 7) << 4))) = hv;
  }
  __syncthreads();  // b0

  // ---- GEMM1: wave w -> n-tiles {2w, 2w+1}; h|o1 overlay x ----
  {
    floatx4 acc[2][4];
#pragma unroll
    for (int q = 0; q < 2; ++q)
#pragma unroll
      for (int mt = 0; mt < 4; ++mt) acc[q][mt] = (floatx4){0.f, 0.f, 0.f, 0.f};
    for (int kt = 0; kt < 8; ++kt) {
      half8 Bx[4];
#pragma unroll
      for (int mt = 0; mt < 4; ++mt) {
        int r = mt * 16 + l15;
        Bx[mt] = *(const half8*)(lds + ((r * 512 + kt * 64 + (l4 << 4)) ^ sw));
      }
#pragma unroll
      for (int q = 0; q < 2; ++q) {
        half8 Wf = *(const half8*)(wsh + WA_OFF + (size_t)(((w * 2 + q) * 8 + kt) * 64 + lane) * 8);
#pragma unroll
        for (int mt = 0; mt < 4; ++mt) acc[q][mt] = MFMA16(Wf, Bx[mt], acc[q][mt]);
      }
    }
    __syncthreads();  // b1: all x reads done before overlay writes
#pragma unroll
    for (int q = 0; q < 2; ++q) {
      int c0 = (w * 2 + q) * 16 + l4 * 4;
      float4 bias = *(const float4*)(wsf + BA_OFF + c0);
#pragma unroll
      for (int mt = 0; mt < 4; ++mt) {
        int r = mt * 16 + l15;
        half4 hv;
#pragma unroll
        for (int i = 0; i < 4; ++i) hv[i] = (f16)fmaxf(acc[q][mt][i] + ((const float*)&bias)[i], 0.f);
        *(half4*)(lds + ((r * 512 + c0 * 2) ^ sw)) = hv;
      }
    }
  }
  __syncthreads();  // b2

  // ---- GEMM2: wave w -> nt=w (h2 -> H2); wave 7 also nt=8 (L1 logits) ----
  {
    floatx4 acc2[4];
    floatx4 accL[4];
#pragma unroll
    for (int mt = 0; mt < 4; ++mt) {
      acc2[mt] = (floatx4){0.f, 0.f, 0.f, 0.f};
      accL[mt] = (floatx4){0.f, 0.f, 0.f, 0.f};
    }
    for (int kt = 0; kt < 4; ++kt) {
      half8 Bh[4];
#pragma unroll
      for (int mt = 0; mt < 4; ++mt) {
        int r = mt * 16 + l15;
        Bh[mt] = *(const half8*)(lds + ((r * 512 + kt * 64 + (l4 << 4)) ^ sw));
      }
      half8 Wf = *(const half8*)(wsh + WB_OFF + (size_t)((w * 4 + kt) * 64 + lane) * 8);
#pragma unroll
      for (int mt = 0; mt < 4; ++mt) acc2[mt] = MFMA16(Wf, Bh[mt], acc2[mt]);
      if (w == 7) {
        half8 WfL = *(const half8*)(wsh + WB_OFF + (size_t)((32 + kt) * 64 + lane) * 8);
#pragma unroll
        for (int mt = 0; mt < 4; ++mt) accL[mt] = MFMA16(WfL, Bh[mt], accL[mt]);
      }
    }
    // epilogue writes H2 / L1 (fresh regions, disjoint from G reads): no pre-barrier
    {
      int c0 = w * 16 + l4 * 4;
      float4 bias = *(const float4*)(wsf + BB_OFF + c0);
#pragma unroll
      for (int mt = 0; mt < 4; ++mt) {
        int r = mt * 16 + l15;
        half4 hv;
#pragma unroll
        for (int i = 0; i < 4; ++i) hv[i] = (f16)fmaxf(acc2[mt][i] + ((const float*)&bias)[i], 0.f);
        *(half4*)(lds + H2_OFF + ((r * 256 + c0 * 2) ^ ((r & 7) << 4))) = hv;
      }
    }
    if (w == 7) {
      float4 biasL = *(const float4*)(wsf + BB_OFF + 128 + l4 * 4);
#pragma unroll
      for (int mt = 0; mt < 4; ++mt) {
        int r = mt * 16 + l15;
        half4 hv;
#pragma unroll
        for (int i = 0; i < 4; ++i) hv[i] = (f16)(accL[mt][i] + ((const float*)&biasL)[i]);
        *(half4*)(lds + L1_OFF + r * 32 + l4 * 8) = hv;
      }
    }
  }
  __syncthreads();  // b3

  // ---- interval b3..b4: GEMM3 (waves 0-3, in-lane c2 -> C2) || softmax+mix (all) ----
  if (w < 4) {
    floatx4 acc3 = (floatx4){0.f, 0.f, 0.f, 0.f};
    int r3 = w * 16 + l15;
#pragma unroll
    for (int kt = 0; kt < 4; ++kt) {
      half8 Bh2 = *(const half8*)(lds + H2_OFF + ((r3 * 256 + kt * 64 + (l4 << 4)) ^ ((r3 & 7) << 4)));
      half8 Wf = *(const half8*)(wsh + WC_OFF + (size_t)(kt * 64 + lane) * 8);
      acc3 = MFMA16(Wf, Bh2, acc3);
    }
    if (lane < 16) {
      float4 bias = *(const float4*)(wsf + BCC_OFF);
      float q0 = acc3[0] + bias.x, q1 = acc3[1] + bias.y;
      float q2 = acc3[2] + bias.z, q3 = acc3[3] + bias.w;
      float m2 = fmaxf(fmaxf(q0, q1), fmaxf(q2, q3));
      float f0 = __expf(q0 - m2), f1 = __expf(q1 - m2);
      float f2 = __expf(q2 - m2), f3 = __expf(q3 - m2);
      float inv2 = 1.f / (f0 + f1 + f2 + f3);
      float4 c2o;
      c2o.x = f0 * inv2; c2o.y = f1 * inv2; c2o.z = f2 * inv2; c2o.w = f3 * inv2;
      *(float4*)(lds + C2_OFF + r3 * 16) = c2o;
    }
  }
  // softmax c1 (in-thread from L1) + mix: in2 overlays DEAD h region, row-sliced by wave
  {
    int r = t >> 3, f = (t >> 1) & 3, hh = t & 1;
    const f16* L1p = (const f16*)(lds + L1_OFF) + r * 16 + f;
    float a0 = (float)L1p[0], a1 = (float)L1p[4], a2 = (float)L1p[8], a3 = (float)L1p[12];
    float m = fmaxf(fmaxf(a0, a1), fmaxf(a2, a3));
    float e0 = __expf(a0 - m), e1 = __expf(a1 - m), e2 = __expf(a2 - m), e3 = __expf(a3 - m);
    float inv = 1.f / (e0 + e1 + e2 + e3);
    f16 c0h = (f16)(e0 * inv), c1h = (f16)(e1 * inv);
    f16 c2h = (f16)(e2 * inv), c3h = (f16)(e3 * inv);
    int swr = (r & 7) << 4;
#pragma unroll
    for (int hi = 0; hi < 2; ++hi) {
      int h8 = hh * 2 + hi;
      half8 o0 = *(const half8*)(lds + ((r * 512 + 256 + 0   + h8 * 16) ^ swr));
      half8 o1v = *(const half8*)(lds + ((r * 512 + 256 + 64  + h8 * 16) ^ swr));
      half8 o2v = *(const half8*)(lds + ((r * 512 + 256 + 128 + h8 * 16) ^ swr));
      half8 o3v = *(const half8*)(lds + ((r * 512 + 256 + 192 + h8 * 16) ^ swr));
      half8 res = o0 * c0h + o1v * c1h + o2v * c2h + o3v * c3h;
      // write to h region (bytes 0..255), disjoint from o1 reads (256..511), same rows
      *(half8*)(lds + ((r * 512 + f * 64 + h8 * 16) ^ swr)) = res;
    }
  }
  __syncthreads();  // b4

  // ---- GEMM4: wave w -> expert e = w&3, half ct = w>>2; fused Wfin + c2 ----
  {
    int e = w & 3, ct = w >> 2;
    half8 Wfv = *(const half8*)(wsh + WF2_OFF + (size_t)((e * 2 + ct) * 64 + lane) * 8);
    float4 bv = *(const float4*)(wsf + BF2_OFF + e * 32 + ct * 16 + l4 * 4);
    float4 wfv = *(const float4*)(wsf + WFIN_OFF + ct * 16 + l4 * 4);
    floatx4 a4[4];
#pragma unroll
    for (int mt = 0; mt < 4; ++mt) a4[mt] = (floatx4){0.f, 0.f, 0.f, 0.f};
#pragma unroll
    for (int mt = 0; mt < 4; ++mt) {
      int r = mt * 16 + l15;
      half8 Bi = *(const half8*)(lds + ((r * 512 + e * 64 + (l4 << 4)) ^ ((r & 7) << 4)));
      a4[mt] = MFMA16(Wfv, Bi, a4[mt]);
    }
#pragma unroll
    for (int mt = 0; mt < 4; ++mt) {
      int r = mt * 16 + l15;
      float s = 0.f;
#pragma unroll
      for (int i = 0; i < 4; ++i)
        s += fmaxf(a4[mt][i] + ((const float*)&bv)[i], 0.f) * ((const float*)&wfv)[i];
      s += __shfl_xor(s, 16);
      s += __shfl_xor(s, 32);
      if (l4 == 0) {
        float c2e = *(const float*)(lds + C2_OFF + r * 16 + e * 4);
        *(float*)(lds + PART_OFF + r * 32 + w * 4) = s * c2e;
      }
    }
  }
  __syncthreads();  // b5

  if (t < 64) {
    float4 p0 = *(const float4*)(lds + PART_OFF + t * 32);
    float4 p1 = *(const float4*)(lds + PART_OFF + t * 32 + 16);
    out[base + t] = wsf[BFIN_OFF] + p0.x + p0.y + p0.z + p0.w + p1.x + p1.y + p1.z + p1.w;
  }
}

extern "C" void kernel_launch(void* const* d_in, const int* in_sizes, int n_in,
                              void* d_out, int out_size, void* d_ws, size_t ws_size,
                              hipStream_t stream) {
  (void)in_sizes; (void)n_in; (void)ws_size;
  const float* x    = (const float*)d_in[0];
  const float* ctx  = (const float*)d_in[1];
  const float* W1   = (const float*)d_in[2];
  const float* b1   = (const float*)d_in[3];
  const float* W2   = (const float*)d_in[4];
  const float* b2   = (const float*)d_in[5];
  const float* W12  = (const float*)d_in[6];
  const float* b12  = (const float*)d_in[7];
  const float* W22  = (const float*)d_in[8];
  const float* b22  = (const float*)d_in[9];
  const float* Wf1  = (const float*)d_in[10];
  const float* bf1  = (const float*)d_in[11];
  const float* Wf2  = (const float*)d_in[12];
  const float* bf2  = (const float*)d_in[13];
  const float* Wfin = (const float*)d_in[14];
  const float* bfin = (const float*)d_in[15];

  f16* wsh = (f16*)d_ws;
  float* wsf = (float*)((char*)d_ws + WSF_BYTE_OFF);

  prep_kernel<<<355, 256, 0, stream>>>(ctx, W1, b1, W2, b2, W12, b12, W22, b22,
                                       Wf1, bf1, Wf2, bf2, Wfin, bfin, wsh, wsf);

  int nblocks = 262144 / BM;  // 4096
  fused_kernel<<<nblocks, 512, 0, stream>>>(x, wsh, wsf, (float*)d_out);
}

// Round 7
// 111.279 us; speedup vs baseline: 2.5511x; 1.0621x over previous
//
#include <hip/hip_runtime.h>
#include <hip/hip_bf16.h>

typedef _Float16 f16;
typedef _Float16 half8 __attribute__((ext_vector_type(8)));
typedef _Float16 half4 __attribute__((ext_vector_type(4)));
typedef float floatx4 __attribute__((ext_vector_type(4)));

#define BM 64

// ---- ws layout (f16 element offsets) ----
#define WA_OFF 0         // 65536 f16 : WaT frag order (NT=16,KT=8)
#define WB_OFF 65536     // 18432 f16 : WbT (NT=9, KT=4)  nt 0-7=W2, 8=W12
#define WC_OFF 83968     // 2048 f16  : WcT (NT=1, KT=4)  rows 0-3 = W22 cols
#define WF2_OFF 86016    // 4096 f16  : Wf2T [4][NT=2,KT=1]
#define WSF_BYTE_OFF 180224
// wsf (float offsets)
#define BA_OFF 0      // 256: b1 | bf1
#define BB_OFF 256    // 144: b2 | b12
#define BCC_OFF 400   // 4  : b22
#define BF2_OFF 404   // 128: bf2
#define WFIN_OFF 532  // 32
#define BFIN_OFF 564  // 1

__global__ __launch_bounds__(256) void prep_kernel(
    const float* __restrict__ ctx, const float* __restrict__ W1,
    const float* __restrict__ b1, const float* __restrict__ W2,
    const float* __restrict__ b2, const float* __restrict__ W12,
    const float* __restrict__ b12, const float* __restrict__ W22,
    const float* __restrict__ b22, const float* __restrict__ Wf1,
    const float* __restrict__ bf1, const float* __restrict__ Wf2,
    const float* __restrict__ bf2, const float* __restrict__ Wfin,
    const float* __restrict__ bfin, f16* __restrict__ wsh,
    float* __restrict__ wsf)
{
  int tid = blockIdx.x * 256 + threadIdx.x;
  if (tid < 65536) {
    int j = tid & 7, l = (tid >> 3) & 63, kt = (tid >> 9) & 7, nt = tid >> 12;
    int k = kt * 32 + ((l >> 4) << 3) + j, n = nt * 16 + (l & 15);
    float v;
    if (n < 128) v = ctx[k] * W1[k * 128 + n];
    else { int c = n - 128; v = Wf1[((c >> 5) * 256 + k) * 32 + (c & 31)]; }
    wsh[tid] = (f16)v;
  } else if (tid < WB_OFF + 18432) {
    int o = tid - WB_OFF;
    int j = o & 7, l = (o >> 3) & 63, kt = (o >> 9) & 3, nt = o >> 11;
    int k = kt * 32 + ((l >> 4) << 3) + j, n = nt * 16 + (l & 15);
    float v = (n < 128) ? W2[k * 128 + n] : W12[k * 16 + (n - 128)];
    wsh[tid] = (f16)v;
  } else if (tid < WC_OFF + 2048) {
    int o = tid - WC_OFF;
    int j = o & 7, l = (o >> 3) & 63, kt = (o >> 9) & 3;
    int k = kt * 32 + ((l >> 4) << 3) + j, n = l & 15;
    float v = (n < 4) ? W22[k * 4 + n] : 0.f;
    wsh[tid] = (f16)v;
  } else if (tid < WF2_OFF + 4096) {
    int o = tid - WF2_OFF;
    int j = o & 7, l = (o >> 3) & 63, ent = o >> 9;
    int e = ent >> 1, nt = ent & 1;
    int k = ((l >> 4) << 3) + j, n = nt * 16 + (l & 15);
    wsh[tid] = (f16)Wf2[(e * 32 + k) * 32 + n];
  } else if (tid < 90112 + 565) {
    int o = tid - 90112;
    float v;
    if (o < 128) v = b1[o];
    else if (o < 256) v = bf1[o - 128];
    else if (o < 384) v = b2[o - 256];
    else if (o < 400) v = b12[o - 384];
    else if (o < 404) v = b22[o - 400];
    else if (o < 532) v = bf2[o - 404];
    else if (o < 564) v = Wfin[o - 532];
    else v = bfin[0];
    wsf[o] = v;
  }
}

#define MFMA16(A, Bv, C) __builtin_amdgcn_mfma_f32_16x16x32_f16(A, Bv, C, 0, 0, 0)

// LDS map (bytes), 51 KB -> 3 blocks/CU of 512 threads = 24 waves/CU:
//  G   0..32767   [64][512B] f16 swz : x -> (h | o1) -> (in2 | o1)
//  H2  32768..49151 [64][256B] f16 swz : h2
//  L1  49152..51199 [64][16] f16 logits ; part [64][8] f32 overlays after use
//  C2  51200..52223 [64][4] f32
#define H2_OFF 32768
#define L1_OFF 49152
#define PART_OFF 49152
#define C2_OFF 51200

// Empirical hipcc rule (R1/R3/R6): VGPR cap ~= 256/arg2, regardless of block
// size. (512,6) capped at ~42 -> 40 VGPR + 66MB spill traffic (R6).
// (512,3) caps at ~85 >= the ~76 this kernel needs -> no spill; occupancy is
// then LDS-limited: 3 blocks x 8 waves = 24 waves/CU (= what R6 reached).
__global__ __launch_bounds__(512, 3) void fused_kernel(
    const float* __restrict__ x, const f16* __restrict__ wsh,
    const float* __restrict__ wsf, float* __restrict__ out)
{
  __shared__ __attribute__((aligned(16))) char lds[52224];
  const int t = threadIdx.x;       // 0..511
  const int lane = t & 63;
  const int w = t >> 6;            // 0..7
  const int l15 = lane & 15;
  const int l4 = lane >> 4;
  const int sw = (l15 & 7) << 4;
  const size_t base = (size_t)blockIdx.x * BM;

  // ---- stage x tile -> G (f16, swizzled) ----
#pragma unroll
  for (int it = 0; it < 4; ++it) {
    int c = it * 512 + t;
    int r = c >> 5;
    int k0 = (c & 31) << 3;
    const float4* xv = (const float4*)(x + (base + (size_t)r) * 256 + k0);
    float4 a = xv[0], b = xv[1];
    half8 hv;
    hv[0] = (f16)a.x; hv[1] = (f16)a.y; hv[2] = (f16)a.z; hv[3] = (f16)a.w;
    hv[4] = (f16)b.x; hv[5] = (f16)b.y; hv[6] = (f16)b.z; hv[7] = (f16)b.w;
    *(half8*)(lds + ((r * 512 + k0 * 2) ^ ((r & 7) << 4))) = hv;
  }
  __syncthreads();  // b0

  // ---- GEMM1: wave w -> n-tiles {2w, 2w+1}; h|o1 overlay x ----
  {
    floatx4 acc[2][4];
#pragma unroll
    for (int q = 0; q < 2; ++q)
#pragma unroll
      for (int mt = 0; mt < 4; ++mt) acc[q][mt] = (floatx4){0.f, 0.f, 0.f, 0.f};
    for (int kt = 0; kt < 8; ++kt) {
      half8 Bx[4];
#pragma unroll
      for (int mt = 0; mt < 4; ++mt) {
        int r = mt * 16 + l15;
        Bx[mt] = *(const half8*)(lds + ((r * 512 + kt * 64 + (l4 << 4)) ^ sw));
      }
#pragma unroll
      for (int q = 0; q < 2; ++q) {
        half8 Wf = *(const half8*)(wsh + WA_OFF + (size_t)(((w * 2 + q) * 8 + kt) * 64 + lane) * 8);
#pragma unroll
        for (int mt = 0; mt < 4; ++mt) acc[q][mt] = MFMA16(Wf, Bx[mt], acc[q][mt]);
      }
    }
    __syncthreads();  // b1: all x reads done before overlay writes
#pragma unroll
    for (int q = 0; q < 2; ++q) {
      int c0 = (w * 2 + q) * 16 + l4 * 4;
      float4 bias = *(const float4*)(wsf + BA_OFF + c0);
#pragma unroll
      for (int mt = 0; mt < 4; ++mt) {
        int r = mt * 16 + l15;
        half4 hv;
#pragma unroll
        for (int i = 0; i < 4; ++i) hv[i] = (f16)fmaxf(acc[q][mt][i] + ((const float*)&bias)[i], 0.f);
        *(half4*)(lds + ((r * 512 + c0 * 2) ^ sw)) = hv;
      }
    }
  }
  __syncthreads();  // b2

  // ---- GEMM2: wave w -> nt=w (h2 -> H2); wave 7 also nt=8 (L1 logits) ----
  {
    floatx4 acc2[4];
    floatx4 accL[4];
#pragma unroll
    for (int mt = 0; mt < 4; ++mt) {
      acc2[mt] = (floatx4){0.f, 0.f, 0.f, 0.f};
      accL[mt] = (floatx4){0.f, 0.f, 0.f, 0.f};
    }
    for (int kt = 0; kt < 4; ++kt) {
      half8 Bh[4];
#pragma unroll
      for (int mt = 0; mt < 4; ++mt) {
        int r = mt * 16 + l15;
        Bh[mt] = *(const half8*)(lds + ((r * 512 + kt * 64 + (l4 << 4)) ^ sw));
      }
      half8 Wf = *(const half8*)(wsh + WB_OFF + (size_t)((w * 4 + kt) * 64 + lane) * 8);
#pragma unroll
      for (int mt = 0; mt < 4; ++mt) acc2[mt] = MFMA16(Wf, Bh[mt], acc2[mt]);
      if (w == 7) {
        half8 WfL = *(const half8*)(wsh + WB_OFF + (size_t)((32 + kt) * 64 + lane) * 8);
#pragma unroll
        for (int mt = 0; mt < 4; ++mt) accL[mt] = MFMA16(WfL, Bh[mt], accL[mt]);
      }
    }
    // epilogue writes H2 / L1 (fresh regions, disjoint from G reads): no pre-barrier
    {
      int c0 = w * 16 + l4 * 4;
      float4 bias = *(const float4*)(wsf + BB_OFF + c0);
#pragma unroll
      for (int mt = 0; mt < 4; ++mt) {
        int r = mt * 16 + l15;
        half4 hv;
#pragma unroll
        for (int i = 0; i < 4; ++i) hv[i] = (f16)fmaxf(acc2[mt][i] + ((const float*)&bias)[i], 0.f);
        *(half4*)(lds + H2_OFF + ((r * 256 + c0 * 2) ^ ((r & 7) << 4))) = hv;
      }
    }
    if (w == 7) {
      float4 biasL = *(const float4*)(wsf + BB_OFF + 128 + l4 * 4);
#pragma unroll
      for (int mt = 0; mt < 4; ++mt) {
        int r = mt * 16 + l15;
        half4 hv;
#pragma unroll
        for (int i = 0; i < 4; ++i) hv[i] = (f16)(accL[mt][i] + ((const float*)&biasL)[i]);
        *(half4*)(lds + L1_OFF + r * 32 + l4 * 8) = hv;
      }
    }
  }
  __syncthreads();  // b3

  // ---- interval b3..b4: GEMM3 (waves 0-3, in-lane c2 -> C2) || softmax+mix (all) ----
  if (w < 4) {
    floatx4 acc3 = (floatx4){0.f, 0.f, 0.f, 0.f};
    int r3 = w * 16 + l15;
#pragma unroll
    for (int kt = 0; kt < 4; ++kt) {
      half8 Bh2 = *(const half8*)(lds + H2_OFF + ((r3 * 256 + kt * 64 + (l4 << 4)) ^ ((r3 & 7) << 4)));
      half8 Wf = *(const half8*)(wsh + WC_OFF + (size_t)(kt * 64 + lane) * 8);
      acc3 = MFMA16(Wf, Bh2, acc3);
    }
    if (lane < 16) {
      float4 bias = *(const float4*)(wsf + BCC_OFF);
      float q0 = acc3[0] + bias.x, q1 = acc3[1] + bias.y;
      float q2 = acc3[2] + bias.z, q3 = acc3[3] + bias.w;
      float m2 = fmaxf(fmaxf(q0, q1), fmaxf(q2, q3));
      float f0 = __expf(q0 - m2), f1 = __expf(q1 - m2);
      float f2 = __expf(q2 - m2), f3 = __expf(q3 - m2);
      float inv2 = 1.f / (f0 + f1 + f2 + f3);
      float4 c2o;
      c2o.x = f0 * inv2; c2o.y = f1 * inv2; c2o.z = f2 * inv2; c2o.w = f3 * inv2;
      *(float4*)(lds + C2_OFF + r3 * 16) = c2o;
    }
  }
  // softmax c1 (in-thread from L1) + mix: in2 overlays DEAD h region, row-sliced
  {
    int r = t >> 3, f = (t >> 1) & 3, hh = t & 1;
    const f16* L1p = (const f16*)(lds + L1_OFF) + r * 16 + f;
    float a0 = (float)L1p[0], a1 = (float)L1p[4], a2 = (float)L1p[8], a3 = (float)L1p[12];
    float m = fmaxf(fmaxf(a0, a1), fmaxf(a2, a3));
    float e0 = __expf(a0 - m), e1 = __expf(a1 - m), e2 = __expf(a2 - m), e3 = __expf(a3 - m);
    float inv = 1.f / (e0 + e1 + e2 + e3);
    f16 c0h = (f16)(e0 * inv), c1h = (f16)(e1 * inv);
    f16 c2h = (f16)(e2 * inv), c3h = (f16)(e3 * inv);
    int swr = (r & 7) << 4;
#pragma unroll
    for (int hi = 0; hi < 2; ++hi) {
      int h8 = hh * 2 + hi;
      half8 o0 = *(const half8*)(lds + ((r * 512 + 256 + 0   + h8 * 16) ^ swr));
      half8 o1v = *(const half8*)(lds + ((r * 512 + 256 + 64  + h8 * 16) ^ swr));
      half8 o2v = *(const half8*)(lds + ((r * 512 + 256 + 128 + h8 * 16) ^ swr));
      half8 o3v = *(const half8*)(lds + ((r * 512 + 256 + 192 + h8 * 16) ^ swr));
      half8 res = o0 * c0h + o1v * c1h + o2v * c2h + o3v * c3h;
      *(half8*)(lds + ((r * 512 + f * 64 + h8 * 16) ^ swr)) = res;
    }
  }
  __syncthreads();  // b4

  // ---- GEMM4: wave w -> expert e = w&3, half ct = w>>2; fused Wfin + c2 ----
  {
    int e = w & 3, ct = w >> 2;
    half8 Wfv = *(const half8*)(wsh + WF2_OFF + (size_t)((e * 2 + ct) * 64 + lane) * 8);
    float4 bv = *(const float4*)(wsf + BF2_OFF + e * 32 + ct * 16 + l4 * 4);
    float4 wfv = *(const float4*)(wsf + WFIN_OFF + ct * 16 + l4 * 4);
    floatx4 a4[4];
#pragma unroll
    for (int mt = 0; mt < 4; ++mt) a4[mt] = (floatx4){0.f, 0.f, 0.f, 0.f};
#pragma unroll
    for (int mt = 0; mt < 4; ++mt) {
      int r = mt * 16 + l15;
      half8 Bi = *(const half8*)(lds + ((r * 512 + e * 64 + (l4 << 4)) ^ ((r & 7) << 4)));
      a4[mt] = MFMA16(Wfv, Bi, a4[mt]);
    }
#pragma unroll
    for (int mt = 0; mt < 4; ++mt) {
      int r = mt * 16 + l15;
      float s = 0.f;
#pragma unroll
      for (int i = 0; i < 4; ++i)
        s += fmaxf(a4[mt][i] + ((const float*)&bv)[i], 0.f) * ((const float*)&wfv)[i];
      s += __shfl_xor(s, 16);
      s += __shfl_xor(s, 32);
      if (l4 == 0) {
        float c2e = *(const float*)(lds + C2_OFF + r * 16 + e * 4);
        *(float*)(lds + PART_OFF + r * 32 + w * 4) = s * c2e;
      }
    }
  }
  __syncthreads();  // b5

  if (t < 64) {
    float4 p0 = *(const float4*)(lds + PART_OFF + t * 32);
    float4 p1 = *(const float4*)(lds + PART_OFF + t * 32 + 16);
    out[base + t] = wsf[BFIN_OFF] + p0.x + p0.y + p0.z + p0.w + p1.x + p1.y + p1.z + p1.w;
  }
}

extern "C" void kernel_launch(void* const* d_in, const int* in_sizes, int n_in,
                              void* d_out, int out_size, void* d_ws, size_t ws_size,
                              hipStream_t stream) {
  (void)in_sizes; (void)n_in; (void)ws_size;
  const float* x    = (const float*)d_in[0];
  const float* ctx  = (const float*)d_in[1];
  const float* W1   = (const float*)d_in[2];
  const float* b1   = (const float*)d_in[3];
  const float* W2   = (const float*)d_in[4];
  const float* b2   = (const float*)d_in[5];
  const float* W12  = (const float*)d_in[6];
  const float* b12  = (const float*)d_in[7];
  const float* W22  = (const float*)d_in[8];
  const float* b22  = (const float*)d_in[9];
  const float* Wf1  = (const float*)d_in[10];
  const float* bf1  = (const float*)d_in[11];
  const float* Wf2  = (const float*)d_in[12];
  const float* bf2  = (const float*)d_in[13];
  const float* Wfin = (const float*)d_in[14];
  const float* bfin = (const float*)d_in[15];

  f16* wsh = (f16*)d_ws;
  float* wsf = (float*)((char*)d_ws + WSF_BYTE_OFF);

  prep_kernel<<<355, 256, 0, stream>>>(ctx, W1, b1, W2, b2, W12, b12, W22, b22,
                                       Wf1, bf1, Wf2, bf2, Wfin, bfin, wsh, wsf);

  int nblocks = 262144 / BM;  // 4096
  fused_kernel<<<nblocks, 512, 0, stream>>>(x, wsh, wsf, (float*)d_out);
}